// Round 6
// baseline (307.621 us; speedup 1.0000x reference)
//
#include <hip/hip_runtime.h>

#define SEQ 2048
#define HID 1024
#define NHEAD 16
#define HDIM 64
#define NB 4
#define NTOK (NB * SEQ)   // 8192
#define NQKV (3 * HID)    // 3072
#define LOG2E 1.44269504088896f
#define QSCALE (0.125f * LOG2E)   // folded into gemm0's Q-column epilogue

typedef __attribute__((ext_vector_type(8))) short bf16x8;
typedef __attribute__((ext_vector_type(4))) float f32x4;

// ---------- helpers ----------

__device__ __forceinline__ void glds16(const void* g, void* l) {
  // async global->LDS, 16B per lane; LDS dest = wave-uniform base + lane*16
  __builtin_amdgcn_global_load_lds(
      (const __attribute__((address_space(1))) void*)g,
      (__attribute__((address_space(3))) void*)l, 16, 0, 0);
}

__device__ __forceinline__ ushort f2bf(float f) {
  union { float f; unsigned int u; } a; a.f = f;
  unsigned int u = a.u;
  return (ushort)((u + 0x7fffu + ((u >> 16) & 1u)) >> 16);  // RNE
}

// pack two fp32 -> bf16x2 (round half up) in 3 VALU via v_perm_b32
__device__ __forceinline__ unsigned int pack2bf_rh(float a, float b) {
  return __builtin_amdgcn_perm(__float_as_uint(b) + 0x8000u,
                               __float_as_uint(a) + 0x8000u, 0x07060302u);
}

// ---------- 1. fused LayerNorm -> bf16 ----------

__global__ __launch_bounds__(256) void ln_kernel(const float* __restrict__ x,
                                                 const float* __restrict__ g,
                                                 const float* __restrict__ be,
                                                 ushort* __restrict__ y) {
  const int row = blockIdx.x;
  const int tid = threadIdx.x;
  const float4 v = ((const float4*)(x + (size_t)row * HID))[tid];
  float s  = v.x + v.y + v.z + v.w;
  float sq = v.x * v.x + v.y * v.y + v.z * v.z + v.w * v.w;
  for (int o = 1; o < 64; o <<= 1) { s += __shfl_xor(s, o, 64); sq += __shfl_xor(sq, o, 64); }
  __shared__ float as_[4], aq_[4];
  const int wv = tid >> 6;
  if ((tid & 63) == 0) { as_[wv] = s; aq_[wv] = sq; }
  __syncthreads();
  s  = as_[0] + as_[1] + as_[2] + as_[3];
  sq = aq_[0] + aq_[1] + aq_[2] + aq_[3];
  const float mu  = s * (1.0f / HID);
  const float var = sq * (1.0f / HID) - mu * mu;
  const float rs  = rsqrtf(var + 1e-12f);
  const float4 gv = ((const float4*)g)[tid];
  const float4 bv = ((const float4*)be)[tid];
  ushort4 o;
  o.x = f2bf((v.x - mu) * rs * gv.x + bv.x);
  o.y = f2bf((v.y - mu) * rs * gv.y + bv.y);
  o.z = f2bf((v.z - mu) * rs * gv.z + bv.z);
  o.w = f2bf((v.w - mu) * rs * gv.w + bv.w);
  ((ushort4*)(y + (size_t)row * HID))[tid] = o;
}

// ---------- 2. transpose + fp32->bf16 convert:  W[R][C] -> WT[C][R] ----------

__global__ __launch_bounds__(256) void transpose_cvt(const float* __restrict__ W,
                                                     ushort* __restrict__ WT,
                                                     int R, int C) {
  __shared__ float t[32][33];
  const int c0 = blockIdx.x * 32, r0 = blockIdx.y * 32;
  const int tx = threadIdx.x & 31, ty = threadIdx.x >> 5;
  for (int j = 0; j < 4; ++j)
    t[ty + j * 8][tx] = W[(size_t)(r0 + ty + j * 8) * C + c0 + tx];
  __syncthreads();
  for (int j = 0; j < 4; ++j)
    WT[(size_t)(c0 + ty + j * 8) * R + r0 + tx] = f2bf(t[tx][ty + j * 8]);
}

// ---------- 2b. V transpose: qkv V-region [tok][h*64+d] -> Vt[b][h][d][s] ----------

__global__ __launch_bounds__(256) void v_transpose(const ushort* __restrict__ qkv,
                                                   ushort* __restrict__ vt) {
  __shared__ ushort t[64][66];
  const int s0 = blockIdx.x * 64, h = blockIdx.y, b = blockIdx.z;
  const size_t tokbase = (size_t)b * SEQ;
  for (int e = 0; e < 2; ++e) {
    const int c = e * 256 + threadIdx.x;
    const int sr = c >> 3, dc = c & 7;
    *(uint4*)&t[sr][dc * 8] =
        *(const uint4*)(qkv + (tokbase + s0 + sr) * NQKV + 2 * HID + h * HDIM + dc * 8);
  }
  __syncthreads();
  for (int e = 0; e < 2; ++e) {
    const int c = e * 256 + threadIdx.x;
    const int dr = c >> 3, sc = c & 7;
    ushort tmp[8];
    for (int j = 0; j < 8; ++j) tmp[j] = t[sc * 8 + j][dr];
    *(uint4*)(vt + ((size_t)(b * NHEAD + h) * HDIM + dr) * SEQ + s0 + sc * 8) = *(uint4*)tmp;
  }
}

// ---------- 3. GEMM  C[M][N] = A[M][K] * Bt[N][K]^T  (bf16 in, fp32 acc) ----------
// MODE 0: C_bf16 = (acc + bias) * qs   (QKV projection; qs = QSCALE for Q cols,
//         folding the attention scale + log2e into Q so flash's MFMA emits logits)
// MODE 1: C_f32  = acc + bias + res    (out projection + residual)

template <int MODE>
__global__ __launch_bounds__(256) void gemm_bt(const ushort* __restrict__ A,
                                               const ushort* __restrict__ Bt,
                                               const float* __restrict__ bias,
                                               const float* __restrict__ resid,
                                               ushort* __restrict__ obf,
                                               float* __restrict__ of32,
                                               int M, int N, int K) {
  __shared__ ushort As[128 * 64];
  __shared__ ushort Bs[128 * 64];
  const int tid = threadIdx.x;
  const int lane = tid & 63, wv = tid >> 6;
  const int q = lane >> 4, li = lane & 15;
  const int m0 = blockIdx.y * 128, n0 = blockIdx.x * 128;
  const int wm = (wv >> 1) * 64, wn = (wv & 1) * 64;
  f32x4 acc[4][4] = {};

  for (int kb = 0; kb < K; kb += 64) {
    for (int e = 0; e < 4; ++e) {
      const int chunk = (wv * 4 + e) * 64 + lane;
      const int row = chunk >> 3, slot = chunk & 7;
      const int kc = slot ^ (row & 7);
      glds16(A  + (size_t)(m0 + row) * K + kb + kc * 8, As + (wv * 4 + e) * 512);
      glds16(Bt + (size_t)(n0 + row) * K + kb + kc * 8, Bs + (wv * 4 + e) * 512);
    }
    __syncthreads();
    for (int ks = 0; ks < 2; ++ks) {
      const int kc = ks * 4 + q;
      bf16x8 af[4], bfr[4];
      for (int mi = 0; mi < 4; ++mi) {
        const int row = wm + mi * 16 + li;
        af[mi] = *(const bf16x8*)(As + (row * 8 + (kc ^ (row & 7))) * 8);
      }
      for (int ni = 0; ni < 4; ++ni) {
        const int row = wn + ni * 16 + li;
        bfr[ni] = *(const bf16x8*)(Bs + (row * 8 + (kc ^ (row & 7))) * 8);
      }
      for (int mi = 0; mi < 4; ++mi)
        for (int ni = 0; ni < 4; ++ni)
          acc[mi][ni] = __builtin_amdgcn_mfma_f32_16x16x32_bf16(af[mi], bfr[ni], acc[mi][ni], 0, 0, 0);
    }
    __syncthreads();
  }

  // per-block uniform Q-scale (tiles are 128-wide; Q region is cols [0,1024))
  const float qs = (MODE == 0 && n0 < HID) ? QSCALE : 1.0f;
  for (int ni = 0; ni < 4; ++ni) {
    const int col = n0 + wn + ni * 16 + li;
    const float bvs = bias[col] * qs;
    for (int mi = 0; mi < 4; ++mi) {
      for (int r = 0; r < 4; ++r) {
        const int row = m0 + wm + mi * 16 + q * 4 + r;
        const float v = fmaf(acc[mi][ni][r], qs, bvs);
        if (MODE == 0) obf[(size_t)row * N + col] = f2bf(v);
        else           of32[(size_t)row * N + col] = v + resid[(size_t)row * N + col];
      }
    }
  }
}

// ---------- 4. flash attention, S^T formulation + K/V double-buffer ----------
// LDS: KV[2][ K 8KB | V 8KB ] = 32 KB -> 5 blocks/CU (was 40 KB / 4 with the
// mask row staged in LDS; mask is now read straight from global — L3-hot, tiny).
// Q staged transiently in KV[0], fragments hoisted to registers (Q pre-scaled by
// 0.125*log2e in gemm0). sigma-permuted K rows so P^T C-layout registers ARE the
// A-fragment of O += P*V (verified R2). Fixed-shift softmax (exact, logits ~|8|).
// Mask applied post-MFMA via fma(mask, log2e, sc) — same VALU as acc-init.
// XCD swizzle: all 16 q-tiles of one (b,h) map to one XCD for K/V L2 reuse.
// NOTE: no min-waves in launch_bounds — (256,4) caused ~850 MB/dispatch scratch
// spill (R3). VGPR is the binding constraint; let the allocator float.

__global__ __launch_bounds__(256) void flash_attn(const ushort* __restrict__ qkv,
                                                  const ushort* __restrict__ vt,
                                                  const float* __restrict__ mask,
                                                  ushort* __restrict__ outa) {
  __shared__ ushort KV[2][8192];   // per buf: [0..4095]=K (sigma rows), [4096..8191]=V^T
  const int tid = threadIdx.x, lane = tid & 63, wv = tid >> 6;
  const int quad = lane >> 4, li = lane & 15;
  const int wq = wv * 32;

  // XCD-aware remap: blocks of one (b,h) share an XCD (id%8 assumed XCD-rr)
  const int L = blockIdx.x + 16 * blockIdx.y + 256 * blockIdx.z;  // 0..1023
  const int xcd = L & 7, rrem = L >> 3;
  const int p = (rrem >> 4) * 8 + xcd;      // (b,h) group 0..63
  const int qt = rrem & 15, h = p & 15, b = p >> 4;

  const size_t tokbase = (size_t)b * SEQ;
  const size_t vtbase = (size_t)(b * NHEAD + h) * HDIM * SEQ;
  const float* mrow = mask + (size_t)b * SEQ;

  // ---- prologue: stage Q into KV[0] ----
  for (int e = 0; e < 4; ++e) {
    const int c = (wv * 4 + e) * 64 + lane;
    const int row = c >> 3, slot = c & 7;
    const int kc = slot ^ (row & 7);
    glds16(qkv + (tokbase + qt * 128 + row) * NQKV + h * HDIM + kc * 8,
           &KV[0][0] + (wv * 4 + e) * 512);
  }
  __syncthreads();  // Q landed

  // hoist Q fragments to registers (loop-invariant)
  bf16x8 qf[2][2];
  for (int ks = 0; ks < 2; ++ks) {
    const int kc = ks * 4 + quad;
    for (int nq = 0; nq < 2; ++nq) {
      const int row = wq + nq * 16 + li;
      qf[ks][nq] = *(const bf16x8*)(&KV[0][0] + (row * 8 + (kc ^ (row & 7))) * 8);
    }
  }
  __syncthreads();  // all Q reads done; KV[0] may be overwritten

  f32x4 accO[2][4] = {};
  float l_st[2] = {0.f, 0.f};

  // stage K (sigma rows) + V^T for tile t into buffer buf
  auto stage_kv = [&](int t, int buf) {
    const int kv0 = t * 64;
    ushort* Kb = &KV[buf][0];
    ushort* Vb = &KV[buf][4096];
    for (int e = 0; e < 2; ++e) {
      const int c = (wv * 2 + e) * 64 + lane;
      const int row = c >> 3, slot = c & 7;
      const int kc = slot ^ (row & 7);
      const int gkv = (row & 0x23) | ((row & 0x0c) << 1) | ((row & 0x10) >> 2);
      glds16(qkv + (tokbase + kv0 + gkv) * NQKV + HID + h * HDIM + kc * 8,
             Kb + (wv * 2 + e) * 512);
      glds16(vt + vtbase + (size_t)row * SEQ + kv0 + kc * 8,
             Vb + (wv * 2 + e) * 512);
    }
  };

  auto compute = [&](int t, int buf) {
    const int kv0 = t * 64;
    const ushort* Kb = &KV[buf][0];
    const ushort* Vb = &KV[buf][4096];

    // issue mask loads first (L3-hot, latency covered by QK^T MFMAs)
    float4 mk[4];
    for (int mkv = 0; mkv < 4; ++mkv)
      mk[mkv] = *(const float4*)(mrow + kv0 + (mkv >> 1) * 32 + quad * 8 + (mkv & 1) * 4);

    // logits^T = K * Q^T   (rows kv via sigma, cols q)
    f32x4 sc[2][4] = {};
    for (int ks = 0; ks < 2; ++ks) {
      const int kc = ks * 4 + quad;
      bf16x8 kf[4];
      for (int mkv = 0; mkv < 4; ++mkv) {
        const int row = mkv * 16 + li;
        kf[mkv] = *(const bf16x8*)(Kb + (row * 8 + (kc ^ (row & 7))) * 8);
      }
      for (int nq = 0; nq < 2; ++nq)
        for (int mkv = 0; mkv < 4; ++mkv)
          sc[nq][mkv] = __builtin_amdgcn_mfma_f32_16x16x32_bf16(kf[mkv], qf[ks][nq], sc[nq][mkv], 0, 0, 0);
    }

    // fixed-shift softmax: p = exp2(logit + mask*log2e), accumulate l, pack bf16
    unsigned int pk[2][4][2];
    for (int nq = 0; nq < 2; ++nq) {
      float rsum = 0.f;
      for (int mkv = 0; mkv < 4; ++mkv) {
        const float p0 = __builtin_amdgcn_exp2f(fmaf(mk[mkv].x, LOG2E, sc[nq][mkv][0]));
        const float p1 = __builtin_amdgcn_exp2f(fmaf(mk[mkv].y, LOG2E, sc[nq][mkv][1]));
        const float p2 = __builtin_amdgcn_exp2f(fmaf(mk[mkv].z, LOG2E, sc[nq][mkv][2]));
        const float p3 = __builtin_amdgcn_exp2f(fmaf(mk[mkv].w, LOG2E, sc[nq][mkv][3]));
        rsum += (p0 + p1) + (p2 + p3);
        pk[nq][mkv][0] = pack2bf_rh(p0, p1);
        pk[nq][mkv][1] = pack2bf_rh(p2, p3);
      }
      rsum += __shfl_xor(rsum, 16, 64);
      rsum += __shfl_xor(rsum, 32, 64);
      l_st[nq] += rsum;
    }

    // O += P * V (A-frag = pk registers, sigma alignment)
    for (int ks = 0; ks < 2; ++ks) {
      const int kc = ks * 4 + quad;
      bf16x8 vf[4];
      for (int nd = 0; nd < 4; ++nd) {
        const int row = nd * 16 + li;
        vf[nd] = *(const bf16x8*)(Vb + (row * 8 + (kc ^ (row & 7))) * 8);
      }
      for (int mq = 0; mq < 2; ++mq) {
        bf16x8 pf;
        ((unsigned int*)&pf)[0] = pk[mq][2 * ks][0];
        ((unsigned int*)&pf)[1] = pk[mq][2 * ks][1];
        ((unsigned int*)&pf)[2] = pk[mq][2 * ks + 1][0];
        ((unsigned int*)&pf)[3] = pk[mq][2 * ks + 1][1];
        for (int nd = 0; nd < 4; ++nd)
          accO[mq][nd] = __builtin_amdgcn_mfma_f32_16x16x32_bf16(pf, vf[nd], accO[mq][nd], 0, 0, 0);
      }
    }
  };

  // ---- main loop: double-buffered, 1 barrier per tile ----
  stage_kv(0, 0);
  for (int t = 0; t < SEQ / 64; t += 2) {
    __syncthreads();              // pf(t)->buf0 landed; reads of buf1 done
    stage_kv(t + 1, 1);
    compute(t, 0);
    __syncthreads();              // pf(t+1)->buf1 landed; reads of buf0 done
    if (t + 2 < SEQ / 64) stage_kv(t + 2, 0);
    compute(t + 1, 1);
  }

  // epilogue: normalize by l (broadcast to accO layout), store bf16
  for (int mq = 0; mq < 2; ++mq)
    for (int r = 0; r < 4; ++r) {
      const float lv = __shfl(l_st[mq], (lane & 48) | (quad * 4 + r), 64);
      const float inv = 1.0f / lv;
      const size_t tok = tokbase + qt * 128 + wq + mq * 16 + quad * 4 + r;
      for (int nd = 0; nd < 4; ++nd)
        outa[tok * HID + h * HDIM + nd * 16 + li] = f2bf(accO[mq][nd][r] * inv);
    }
}

// ---------- launch ----------

extern "C" void kernel_launch(void* const* d_in, const int* in_sizes, int n_in,
                              void* d_out, int out_size, void* d_ws, size_t ws_size,
                              hipStream_t stream) {
  const float* hidden = (const float*)d_in[0];
  const float* mask   = (const float*)d_in[1];
  const float* gamma  = (const float*)d_in[2];
  const float* beta   = (const float*)d_in[3];
  const float* Wqkv   = (const float*)d_in[4];
  const float* bqkv   = (const float*)d_in[5];
  const float* Wout   = (const float*)d_in[6];
  const float* bout   = (const float*)d_in[7];
  float* out = (float*)d_out;

  char* ws = (char*)d_ws;
  ushort* x_bf  = (ushort*)(ws);                       // 16 MB (dead after gemm0)
  ushort* vtb   = (ushort*)(ws);                       // 16 MB (reuses x_bf region)
  ushort* wqkvT = (ushort*)(ws + ((size_t)16 << 20));  //  6 MB (dead after gemm0)
  ushort* woutT = (ushort*)(ws + ((size_t)22 << 20));  //  2 MB
  ushort* qkvb  = (ushort*)(ws + ((size_t)24 << 20));  // 48 MB
  ushort* attnb = (ushort*)(ws + ((size_t)72 << 20));  // 16 MB

  ln_kernel<<<NTOK, 256, 0, stream>>>(hidden, gamma, beta, x_bf);
  transpose_cvt<<<dim3(NQKV / 32, HID / 32), 256, 0, stream>>>(Wqkv, wqkvT, HID, NQKV);
  transpose_cvt<<<dim3(HID / 32, HID / 32), 256, 0, stream>>>(Wout, woutT, HID, HID);
  gemm_bt<0><<<dim3(NQKV / 128, NTOK / 128), 256, 0, stream>>>(
      x_bf, wqkvT, bqkv, nullptr, qkvb, nullptr, NTOK, NQKV, HID);
  v_transpose<<<dim3(SEQ / 64, NHEAD, NB), 256, 0, stream>>>(qkvb, vtb);
  flash_attn<<<dim3(SEQ / 128, NHEAD, NB), 256, 0, stream>>>(qkvb, vtb, mask, attnb);
  gemm_bt<1><<<dim3(HID / 128, NTOK / 128), 256, 0, stream>>>(
      attnb, woutT, bout, hidden, nullptr, out, NTOK, HID, HID);
}

// Round 7
// 302.184 us; speedup vs baseline: 1.0180x; 1.0180x over previous
//
#include <hip/hip_runtime.h>

#define SEQ 2048
#define HID 1024
#define NHEAD 16
#define HDIM 64
#define NB 4
#define NTOK (NB * SEQ)   // 8192
#define NQKV (3 * HID)    // 3072
#define LOG2E 1.44269504088896f
#define QSCALE (0.125f * LOG2E)   // folded into gemm0's Q-column epilogue

typedef __attribute__((ext_vector_type(8))) short bf16x8;
typedef __attribute__((ext_vector_type(4))) float f32x4;

// ---------- helpers ----------

__device__ __forceinline__ void glds16(const void* g, void* l) {
  // async global->LDS, 16B per lane; LDS dest = wave-uniform base + lane*16
  __builtin_amdgcn_global_load_lds(
      (const __attribute__((address_space(1))) void*)g,
      (__attribute__((address_space(3))) void*)l, 16, 0, 0);
}

__device__ __forceinline__ ushort f2bf(float f) {
  union { float f; unsigned int u; } a; a.f = f;
  unsigned int u = a.u;
  return (ushort)((u + 0x7fffu + ((u >> 16) & 1u)) >> 16);  // RNE
}

// pack two fp32 -> bf16x2 (round half up) in 3 VALU via v_perm_b32
__device__ __forceinline__ unsigned int pack2bf_rh(float a, float b) {
  return __builtin_amdgcn_perm(__float_as_uint(b) + 0x8000u,
                               __float_as_uint(a) + 0x8000u, 0x07060302u);
}

// ---------- 1. fused LayerNorm -> bf16 ----------

__global__ __launch_bounds__(256) void ln_kernel(const float* __restrict__ x,
                                                 const float* __restrict__ g,
                                                 const float* __restrict__ be,
                                                 ushort* __restrict__ y) {
  const int row = blockIdx.x;
  const int tid = threadIdx.x;
  const float4 v = ((const float4*)(x + (size_t)row * HID))[tid];
  float s  = v.x + v.y + v.z + v.w;
  float sq = v.x * v.x + v.y * v.y + v.z * v.z + v.w * v.w;
  for (int o = 1; o < 64; o <<= 1) { s += __shfl_xor(s, o, 64); sq += __shfl_xor(sq, o, 64); }
  __shared__ float as_[4], aq_[4];
  const int wv = tid >> 6;
  if ((tid & 63) == 0) { as_[wv] = s; aq_[wv] = sq; }
  __syncthreads();
  s  = as_[0] + as_[1] + as_[2] + as_[3];
  sq = aq_[0] + aq_[1] + aq_[2] + aq_[3];
  const float mu  = s * (1.0f / HID);
  const float var = sq * (1.0f / HID) - mu * mu;
  const float rs  = rsqrtf(var + 1e-12f);
  const float4 gv = ((const float4*)g)[tid];
  const float4 bv = ((const float4*)be)[tid];
  ushort4 o;
  o.x = f2bf((v.x - mu) * rs * gv.x + bv.x);
  o.y = f2bf((v.y - mu) * rs * gv.y + bv.y);
  o.z = f2bf((v.z - mu) * rs * gv.z + bv.z);
  o.w = f2bf((v.w - mu) * rs * gv.w + bv.w);
  ((ushort4*)(y + (size_t)row * HID))[tid] = o;
}

// ---------- 2. transpose + fp32->bf16 convert, both weights in one launch ----------
// z=0: W_qkv [HID][NQKV] -> [NQKV][HID]; z=1: W_out [HID][HID] -> [HID][HID]

__global__ __launch_bounds__(256) void transpose_cvt2(const float* __restrict__ W0,
                                                      ushort* __restrict__ T0,
                                                      const float* __restrict__ W1,
                                                      ushort* __restrict__ T1) {
  const float* W; ushort* WT; int C;
  if (blockIdx.z == 0) { W = W0; WT = T0; C = NQKV; }
  else { if (blockIdx.x >= HID / 32) return; W = W1; WT = T1; C = HID; }
  const int R = HID;
  __shared__ float t[32][33];
  const int c0 = blockIdx.x * 32, r0 = blockIdx.y * 32;
  const int tx = threadIdx.x & 31, ty = threadIdx.x >> 5;
  for (int j = 0; j < 4; ++j)
    t[ty + j * 8][tx] = W[(size_t)(r0 + ty + j * 8) * C + c0 + tx];
  __syncthreads();
  for (int j = 0; j < 4; ++j)
    WT[(size_t)(c0 + ty + j * 8) * R + r0 + tx] = f2bf(t[tx][ty + j * 8]);
}

// ---------- 2b. V transpose: qkv V-region [tok][h*64+d] -> Vt[b][h][d][s] ----------

__global__ __launch_bounds__(256) void v_transpose(const ushort* __restrict__ qkv,
                                                   ushort* __restrict__ vt) {
  __shared__ ushort t[64][66];
  const int s0 = blockIdx.x * 64, h = blockIdx.y, b = blockIdx.z;
  const size_t tokbase = (size_t)b * SEQ;
  for (int e = 0; e < 2; ++e) {
    const int c = e * 256 + threadIdx.x;
    const int sr = c >> 3, dc = c & 7;
    *(uint4*)&t[sr][dc * 8] =
        *(const uint4*)(qkv + (tokbase + s0 + sr) * NQKV + 2 * HID + h * HDIM + dc * 8);
  }
  __syncthreads();
  for (int e = 0; e < 2; ++e) {
    const int c = e * 256 + threadIdx.x;
    const int dr = c >> 3, sc = c & 7;
    ushort tmp[8];
    for (int j = 0; j < 8; ++j) tmp[j] = t[sc * 8 + j][dr];
    *(uint4*)(vt + ((size_t)(b * NHEAD + h) * HDIM + dr) * SEQ + s0 + sc * 8) = *(uint4*)tmp;
  }
}

// ---------- 3. GEMM  C[M][N] = A[M][K] * Bt[N][K]^T  (bf16 in, fp32 acc) ----------
// MODE 0: C_bf16 = (acc + bias) * qs   (QKV projection; qs = QSCALE for Q cols,
//         folding the attention scale + log2e into Q so flash's MFMA emits logits)
// MODE 1: C_f32  = acc + bias + res    (out projection + residual)

template <int MODE>
__global__ __launch_bounds__(256) void gemm_bt(const ushort* __restrict__ A,
                                               const ushort* __restrict__ Bt,
                                               const float* __restrict__ bias,
                                               const float* __restrict__ resid,
                                               ushort* __restrict__ obf,
                                               float* __restrict__ of32,
                                               int M, int N, int K) {
  __shared__ ushort As[128 * 64];
  __shared__ ushort Bs[128 * 64];
  const int tid = threadIdx.x;
  const int lane = tid & 63, wv = tid >> 6;
  const int q = lane >> 4, li = lane & 15;
  const int m0 = blockIdx.y * 128, n0 = blockIdx.x * 128;
  const int wm = (wv >> 1) * 64, wn = (wv & 1) * 64;
  f32x4 acc[4][4] = {};

  for (int kb = 0; kb < K; kb += 64) {
    for (int e = 0; e < 4; ++e) {
      const int chunk = (wv * 4 + e) * 64 + lane;
      const int row = chunk >> 3, slot = chunk & 7;
      const int kc = slot ^ (row & 7);
      glds16(A  + (size_t)(m0 + row) * K + kb + kc * 8, As + (wv * 4 + e) * 512);
      glds16(Bt + (size_t)(n0 + row) * K + kb + kc * 8, Bs + (wv * 4 + e) * 512);
    }
    __syncthreads();
    for (int ks = 0; ks < 2; ++ks) {
      const int kc = ks * 4 + q;
      bf16x8 af[4], bfr[4];
      for (int mi = 0; mi < 4; ++mi) {
        const int row = wm + mi * 16 + li;
        af[mi] = *(const bf16x8*)(As + (row * 8 + (kc ^ (row & 7))) * 8);
      }
      for (int ni = 0; ni < 4; ++ni) {
        const int row = wn + ni * 16 + li;
        bfr[ni] = *(const bf16x8*)(Bs + (row * 8 + (kc ^ (row & 7))) * 8);
      }
      for (int mi = 0; mi < 4; ++mi)
        for (int ni = 0; ni < 4; ++ni)
          acc[mi][ni] = __builtin_amdgcn_mfma_f32_16x16x32_bf16(af[mi], bfr[ni], acc[mi][ni], 0, 0, 0);
    }
    __syncthreads();
  }

  // per-block uniform Q-scale (tiles are 128-wide; Q region is cols [0,1024))
  const float qs = (MODE == 0 && n0 < HID) ? QSCALE : 1.0f;
  for (int ni = 0; ni < 4; ++ni) {
    const int col = n0 + wn + ni * 16 + li;
    const float bvs = bias[col] * qs;
    for (int mi = 0; mi < 4; ++mi) {
      for (int r = 0; r < 4; ++r) {
        const int row = m0 + wm + mi * 16 + q * 4 + r;
        const float v = fmaf(acc[mi][ni][r], qs, bvs);
        if (MODE == 0) obf[(size_t)row * N + col] = f2bf(v);
        else           of32[(size_t)row * N + col] = v + resid[(size_t)row * N + col];
      }
    }
  }
}

// ---------- 4. flash attention, S^T formulation + K/V double-buffer ----------
// LDS: KV[2][ K 8KB | V 8KB ] = 32 KB. sigma-permuted K rows so P^T C-layout
// registers ARE the A-fragment of O += P*V. Fixed-shift softmax (exact; R5).
// l computed BY THE MATRIX PIPE: accL += P x ones (B-operand = bf16 1.0 splat)
// — removes the per-tile add-tree + 2 cross-lane shuffles (the longest serial
// chain) and puts l directly in accO layout for the epilogue. All LDS fragment
// offsets hoisted out of the K-loop. XCD swizzle keeps K/V L2-resident (R6:
// FETCH 139->25 MB). No min-waves in launch_bounds (R3 spill lesson).

__global__ __launch_bounds__(256) void flash_attn(const ushort* __restrict__ qkv,
                                                  const ushort* __restrict__ vt,
                                                  const float* __restrict__ mask,
                                                  ushort* __restrict__ outa) {
  __shared__ ushort KV[2][8192];   // per buf: [0..4095]=K (sigma rows), [4096..8191]=V^T
  const int tid = threadIdx.x, lane = tid & 63, wv = tid >> 6;
  const int quad = lane >> 4, li = lane & 15;
  const int wq = wv * 32;

  // XCD-aware remap: blocks of one (b,h) share an XCD (id%8 assumed XCD-rr)
  const int L = blockIdx.x + 16 * blockIdx.y + 256 * blockIdx.z;  // 0..1023
  const int xcd = L & 7, rrem = L >> 3;
  const int p = (rrem >> 4) * 8 + xcd;      // (b,h) group 0..63
  const int qt = rrem & 15, h = p & 15, b = p >> 4;

  const size_t tokbase = (size_t)b * SEQ;
  const size_t vtbase = (size_t)(b * NHEAD + h) * HDIM * SEQ;
  const float* mrow = mask + (size_t)b * SEQ;

  // ---- prologue: stage Q into KV[0] ----
  for (int e = 0; e < 4; ++e) {
    const int c = (wv * 4 + e) * 64 + lane;
    const int row = c >> 3, slot = c & 7;
    const int kc = slot ^ (row & 7);
    glds16(qkv + (tokbase + qt * 128 + row) * NQKV + h * HDIM + kc * 8,
           &KV[0][0] + (wv * 4 + e) * 512);
  }
  __syncthreads();  // Q landed

  // hoist Q fragments to registers (loop-invariant)
  bf16x8 qf[2][2];
  for (int ks = 0; ks < 2; ++ks) {
    const int kc = ks * 4 + quad;
    for (int nq = 0; nq < 2; ++nq) {
      const int row = wq + nq * 16 + li;
      qf[ks][nq] = *(const bf16x8*)(&KV[0][0] + (row * 8 + (kc ^ (row & 7))) * 8);
    }
  }
  __syncthreads();  // all Q reads done; KV[0] may be overwritten

  // hoisted LDS fragment offsets (ushort elements), loop-invariant
  int koff[2][4], voff[2][4];
  for (int ks = 0; ks < 2; ++ks) {
    const int kc = ks * 4 + quad;
    for (int i = 0; i < 4; ++i) {
      const int row = i * 16 + li;
      koff[ks][i] = (row * 8 + (kc ^ (row & 7))) * 8;
      voff[ks][i] = koff[ks][i] + 4096;   // V^T shares the row pattern, +8KB
    }
  }
  // hoisted global staging addresses (per-lane, kv0=0)
  const ushort* ksrc[2];
  const ushort* vsrc[2];
  for (int e = 0; e < 2; ++e) {
    const int c = (wv * 2 + e) * 64 + lane;
    const int row = c >> 3, slot = c & 7;
    const int kc = slot ^ (row & 7);
    const int gkv = (row & 0x23) | ((row & 0x0c) << 1) | ((row & 0x10) >> 2);
    ksrc[e] = qkv + (tokbase + gkv) * NQKV + HID + h * HDIM + kc * 8;
    vsrc[e] = vt + vtbase + (size_t)row * SEQ + kc * 8;
  }

  const unsigned int one2 = 0x3F803F80u;  // bf16 1.0 x2
  bf16x8 ones;
  for (int j = 0; j < 4; ++j) ((unsigned int*)&ones)[j] = one2;

  f32x4 accO[2][4] = {};
  f32x4 accL[2] = {};   // l per q-row, accO C-layout (all 16 n-cols identical)

  auto stage_kv = [&](int t, int buf) {
    const int kv0 = t * 64;
    for (int e = 0; e < 2; ++e) {
      glds16(ksrc[e] + (size_t)kv0 * NQKV, &KV[buf][0] + (wv * 2 + e) * 512);
      glds16(vsrc[e] + kv0,                &KV[buf][4096] + (wv * 2 + e) * 512);
    }
  };

  auto compute = [&](int t, int buf) {
    const int kv0 = t * 64;
    const ushort* Kb = &KV[buf][0];

    // mask loads first (L2-hot; latency covered by QK^T MFMAs)
    float4 mk[4];
    for (int mkv = 0; mkv < 4; ++mkv)
      mk[mkv] = *(const float4*)(mrow + kv0 + (mkv >> 1) * 32 + quad * 8 + (mkv & 1) * 4);

    // logits^T = K * Q^T   (rows kv via sigma, cols q)
    f32x4 sc[2][4] = {};
    for (int ks = 0; ks < 2; ++ks) {
      bf16x8 kf[4];
      for (int mkv = 0; mkv < 4; ++mkv)
        kf[mkv] = *(const bf16x8*)(Kb + koff[ks][mkv]);
      for (int nq = 0; nq < 2; ++nq)
        for (int mkv = 0; mkv < 4; ++mkv)
          sc[nq][mkv] = __builtin_amdgcn_mfma_f32_16x16x32_bf16(kf[mkv], qf[ks][nq], sc[nq][mkv], 0, 0, 0);
    }

    // fixed-shift softmax: p = exp2(logit + mask*log2e), pack bf16 (no reduction!)
    unsigned int pk[2][4][2];
    for (int nq = 0; nq < 2; ++nq) {
      for (int mkv = 0; mkv < 4; ++mkv) {
        const float p0 = __builtin_amdgcn_exp2f(fmaf(mk[mkv].x, LOG2E, sc[nq][mkv][0]));
        const float p1 = __builtin_amdgcn_exp2f(fmaf(mk[mkv].y, LOG2E, sc[nq][mkv][1]));
        const float p2 = __builtin_amdgcn_exp2f(fmaf(mk[mkv].z, LOG2E, sc[nq][mkv][2]));
        const float p3 = __builtin_amdgcn_exp2f(fmaf(mk[mkv].w, LOG2E, sc[nq][mkv][3]));
        pk[nq][mkv][0] = pack2bf_rh(p0, p1);
        pk[nq][mkv][1] = pack2bf_rh(p2, p3);
      }
    }

    // O += P * V ; l += P * 1  (A-frag = pk registers, sigma alignment)
    for (int ks = 0; ks < 2; ++ks) {
      bf16x8 vf[4];
      for (int nd = 0; nd < 4; ++nd)
        vf[nd] = *(const bf16x8*)(Kb + voff[ks][nd]);
      for (int mq = 0; mq < 2; ++mq) {
        bf16x8 pf;
        ((unsigned int*)&pf)[0] = pk[mq][2 * ks][0];
        ((unsigned int*)&pf)[1] = pk[mq][2 * ks][1];
        ((unsigned int*)&pf)[2] = pk[mq][2 * ks + 1][0];
        ((unsigned int*)&pf)[3] = pk[mq][2 * ks + 1][1];
        for (int nd = 0; nd < 4; ++nd)
          accO[mq][nd] = __builtin_amdgcn_mfma_f32_16x16x32_bf16(pf, vf[nd], accO[mq][nd], 0, 0, 0);
        accL[mq] = __builtin_amdgcn_mfma_f32_16x16x32_bf16(pf, ones, accL[mq], 0, 0, 0);
      }
    }
  };

  // ---- main loop: double-buffered, 1 barrier per tile ----
  stage_kv(0, 0);
  for (int t = 0; t < SEQ / 64; t += 2) {
    __syncthreads();              // pf(t)->buf0 landed; reads of buf1 done
    stage_kv(t + 1, 1);
    compute(t, 0);
    __syncthreads();              // pf(t+1)->buf1 landed; reads of buf0 done
    if (t + 2 < SEQ / 64) stage_kv(t + 2, 0);
    compute(t + 1, 1);
  }

  // epilogue: normalize by l (already in accO layout — no shuffles), store bf16
  for (int mq = 0; mq < 2; ++mq)
    for (int r = 0; r < 4; ++r) {
      const float inv = 1.0f / accL[mq][r];
      const size_t tok = tokbase + qt * 128 + wq + mq * 16 + quad * 4 + r;
      for (int nd = 0; nd < 4; ++nd)
        outa[tok * HID + h * HDIM + nd * 16 + li] = f2bf(accO[mq][nd][r] * inv);
    }
}

// ---------- launch ----------

extern "C" void kernel_launch(void* const* d_in, const int* in_sizes, int n_in,
                              void* d_out, int out_size, void* d_ws, size_t ws_size,
                              hipStream_t stream) {
  const float* hidden = (const float*)d_in[0];
  const float* mask   = (const float*)d_in[1];
  const float* gamma  = (const float*)d_in[2];
  const float* beta   = (const float*)d_in[3];
  const float* Wqkv   = (const float*)d_in[4];
  const float* bqkv   = (const float*)d_in[5];
  const float* Wout   = (const float*)d_in[6];
  const float* bout   = (const float*)d_in[7];
  float* out = (float*)d_out;

  char* ws = (char*)d_ws;
  ushort* x_bf  = (ushort*)(ws);                       // 16 MB (dead after gemm0)
  ushort* vtb   = (ushort*)(ws);                       // 16 MB (reuses x_bf region)
  ushort* wqkvT = (ushort*)(ws + ((size_t)16 << 20));  //  6 MB
  ushort* woutT = (ushort*)(ws + ((size_t)22 << 20));  //  2 MB
  ushort* qkvb  = (ushort*)(ws + ((size_t)24 << 20));  // 48 MB
  ushort* attnb = (ushort*)(ws + ((size_t)72 << 20));  // 16 MB

  ln_kernel<<<NTOK, 256, 0, stream>>>(hidden, gamma, beta, x_bf);
  transpose_cvt2<<<dim3(NQKV / 32, HID / 32, 2), 256, 0, stream>>>(Wqkv, wqkvT, Wout, woutT);
  gemm_bt<0><<<dim3(NQKV / 128, NTOK / 128), 256, 0, stream>>>(
      x_bf, wqkvT, bqkv, nullptr, qkvb, nullptr, NTOK, NQKV, HID);
  v_transpose<<<dim3(SEQ / 64, NHEAD, NB), 256, 0, stream>>>(qkvb, vtb);
  flash_attn<<<dim3(SEQ / 128, NHEAD, NB), 256, 0, stream>>>(qkvb, vtb, mask, attnb);
  gemm_bt<1><<<dim3(HID / 128, NTOK / 128), 256, 0, stream>>>(
      attnb, woutT, bout, hidden, nullptr, out, NTOK, HID, HID);
}